// Round 9
// baseline (155.833 us; speedup 1.0000x reference)
//
#include <hip/hip_runtime.h>
#include <hip/hip_bf16.h>
#include <math.h>

#define Nn 64
#define Cn 64
#define Tn 64
#define Vn 25
#define Sn 8
#define ICn 8
#define Wn 3
#define WVn 75

typedef __attribute__((ext_vector_type(8))) short s16x8;   // 8 bf16 (4 VGPR)
typedef __attribute__((ext_vector_type(4))) short s16x4;   // 4 bf16 (2 VGPR)
typedef __attribute__((ext_vector_type(4))) float f32x4;   // MFMA acc

#define MFMA16(a, b, c) __builtin_amdgcn_mfma_f32_16x16x32_bf16(a, b, c, 0, 0, 0)

static __device__ inline unsigned short f2bf(float f) {
    __hip_bfloat16 h = __float2bfloat16(f);
    return *reinterpret_cast<unsigned short*>(&h);
}
static __device__ inline float bf2f(unsigned short u) {
    union { unsigned int i; float f; } x;
    x.i = ((unsigned int)u) << 16;
    return x.f;
}

// ---------------------------------------------------------------------------
// K1: per (n,c) reductions over x rows (collapsed diff/gate branch).
// n==0 blocks also convert out_w/ff_w rows to bf16 (folded k_conv).
// ---------------------------------------------------------------------------
__global__ __launch_bounds__(64) void k_red(const float* __restrict__ x,
                                            const float* __restrict__ ga,
                                            const float* __restrict__ ow,
                                            const float* __restrict__ fw,
                                            float* __restrict__ red,
                                            unsigned short* __restrict__ owb,
                                            unsigned short* __restrict__ fwb) {
    const int c = blockIdx.x, n = blockIdx.y;
    const int lane = threadIdx.x;
    if (n == 0) {
        for (int j = lane; j < 512; j += 64) owb[c * 512 + j] = f2bf(ow[c * 512 + j]);
        fwb[c * 64 + lane] = f2bf(fw[c * 64 + lane]);
    }
    float rs = 0.f, r0 = 0.f, r63 = 0.f, xg = 0.f;
    if (lane < Vn) {
        const float* row = x + ((size_t)(n * Cn + c) * Vn + lane) * Tn;
        float g = 0.f;
        for (int j = 0; j < Vn; ++j) g += ga[lane * Vn + j];
        for (int t = 0; t < Tn; ++t) rs += row[t];
        r0 = row[0];
        r63 = row[Tn - 1];
        xg = rs * g;
    }
    for (int off = 32; off > 0; off >>= 1) {
        rs += __shfl_down(rs, off);
        r0 += __shfl_down(r0, off);
        r63 += __shfl_down(r63, off);
        xg += __shfl_down(xg, off);
    }
    if (lane == 0) {
        float* p = red + (size_t)(n * Cn + c) * 4;
        p[0] = rs; p[1] = r0; p[2] = r63; p[3] = xg;
    }
}

// ---------------------------------------------------------------------------
// K_proj: q/k conv1x1 projections -> bf16, layout [n][v][t][o] (o fastest).
// ---------------------------------------------------------------------------
__global__ __launch_bounds__(256) void k_proj(
    const float* __restrict__ x,
    const float* __restrict__ in_w, const float* __restrict__ in_b,
    const float* __restrict__ inup_w, const float* __restrict__ inup_b,
    unsigned short* __restrict__ pk, unsigned short* __restrict__ pq) {
    const int v = blockIdx.x, n = blockIdx.y;
    const int tid = threadIdx.x;
    __shared__ float xs[64 * 65];   // [c][t]
    __shared__ float wk[64 * 65];   // [o][c]
    __shared__ float wq[64 * 65];

    for (int i = tid; i < 4096; i += 256) {
        int o = i >> 6, c = i & 63;
        wk[o * 65 + c] = in_w[i];
        wq[o * 65 + c] = inup_w[i];
    }
    for (int i = tid; i < 4096; i += 256) {
        int c = i >> 6, t = i & 63;
        xs[c * 65 + t] = x[((size_t)(n * Cn + c) * Vn + v) * Tn + t];
    }
    __syncthreads();

    const int o = tid & 63, tq = tid >> 6;   // wave-uniform tq
    float ak[16], aq[16];
#pragma unroll
    for (int t = 0; t < 16; ++t) { ak[t] = 0.f; aq[t] = 0.f; }
    for (int c = 0; c < 64; ++c) {
        float wkc = wk[o * 65 + c], wqc = wq[o * 65 + c];
        const float* xr = &xs[c * 65 + tq * 16];   // uniform address
#pragma unroll
        for (int t = 0; t < 16; ++t) {
            float xv = xr[t];
            ak[t] += wkc * xv;
            aq[t] += wqc * xv;
        }
    }
    const float bk = in_b[o], bq = inup_b[o];
    const size_t base = ((size_t)(n * Vn + v) * Tn + tq * 16) * 64 + o;
#pragma unroll
    for (int t = 0; t < 16; ++t) {
        pk[base + t * 64] = f2bf(ak[t] + bk);
        pq[base + t * 64] = f2bf(aq[t] + bq);
    }
}

// ---------------------------------------------------------------------------
// K_att3 (MFMA): fused attention logits + softmax + gate + att0 -> attB.
// Gate computation folded in (from red_ws; hidden under staging/MFMA).
// ---------------------------------------------------------------------------
__global__ __launch_bounds__(256) void k_att3(
    const unsigned short* __restrict__ pq, const unsigned short* __restrict__ pk,
    const float* __restrict__ inup_b, const float* __restrict__ graph,
    const float* __restrict__ att0, const float* __restrict__ red,
    const float* __restrict__ diff_w, const float* __restrict__ diff_b,
    unsigned short* __restrict__ attB) {
    const int n = blockIdx.x, s = blockIdx.y;
    const int tid = threadIdx.x;
    const int lane = tid & 63, wv = tid >> 6;
    const int r16 = lane & 15, g4 = lane >> 4;

    __shared__ unsigned short QS[25 * 536];   // [uu][slot 0..66][cc]
    __shared__ unsigned short KS[32 * 512];   // [v][(t^(v&7))*8+cc]
    __shared__ float attL[80 * 33];
    __shared__ float gp4[8][4];
    __shared__ float g3[3];

    // ---- gate partials (folded k_gate), parallel to staging
    if (tid < 8) {
        const int oc = s * ICn + tid;
        float a = 0.f;
        for (int c = 0; c < Cn; ++c)
            a += red[(n * Cn + c) * 4 + 3] * diff_w[oc * Cn + c];
        gp4[tid][0] = a + 1600.f * diff_b[oc];
        gp4[tid][1] = red[(n * Cn + oc) * 4 + 0];
        gp4[tid][2] = red[(n * Cn + oc) * 4 + 1];
        gp4[tid][3] = red[(n * Cn + oc) * 4 + 2];
    }
    for (int i = tid; i < 2048; i += 256) {
        const int t = i & 63, v = i >> 6;
        s16x8 d = (s16x8){0, 0, 0, 0, 0, 0, 0, 0};
        if (v < Vn)
            d = *(const s16x8*)(pk + (((size_t)(n * Vn + v) * Tn + t) << 6) + s * ICn);
        *(s16x8*)&KS[v * 512 + ((t ^ (v & 7)) << 3)] = d;
    }
    for (int i = tid; i < 1600; i += 256) {
        const int t = i & 63, uu = i >> 6;
        const s16x8 d = *(const s16x8*)(pq +
            (((size_t)(n * Vn + uu) * Tn + t) << 6) + s * ICn);
        *(s16x8*)&QS[uu * 536 + (t + 1) * 8] = d;
    }
    if (tid < 50) {  // bias edge slots 0 and 65
        const int uu = tid >> 1, slot = (tid & 1) * 65;
#pragma unroll
        for (int cc = 0; cc < ICn; ++cc)
            QS[uu * 536 + slot * 8 + cc] = f2bf(inup_b[s * ICn + cc]);
    }
    __syncthreads();

    for (int tile = wv; tile < 10; tile += 4) {
        const int mt = tile >> 1, nt = tile & 1;
        const int u = mt * 16 + r16;
        const int w = u / 25, uu = u % 25;
        const int v = nt * 16 + r16;
        const unsigned short* qbase = &QS[uu * 536 + (g4 + w) * 8];
        const unsigned short* kbase = &KS[v * 512];
        f32x4 acc = (f32x4){0.f, 0.f, 0.f, 0.f};
#pragma unroll
        for (int kb = 0; kb < 16; ++kb) {
            const s16x8 af = *(const s16x8*)(qbase + kb * 32);
            const s16x8 bf = *(const s16x8*)(kbase + (((kb * 4 + g4) ^ (v & 7)) << 3));
            acc = MFMA16(af, bf, acc);
        }
#pragma unroll
        for (int r = 0; r < 4; ++r)
            attL[(mt * 16 + g4 * 4 + r) * 33 + v] = acc[r];
    }
    if (tid == 0) {  // finish gate (parallel to other waves' MFMA)
        float sumd2 = 0.f, rsum = 0.f, rr0 = 0.f, rr63 = 0.f;
#pragma unroll
        for (int cc = 0; cc < 8; ++cc) {
            sumd2 += gp4[cc][0]; rsum += gp4[cc][1];
            rr0 += gp4[cc][2]; rr63 += gp4[cc][3];
        }
        const float inv = 1.f / 12800.f;
        g3[0] = 1.f / (1.f + expf(-(sumd2 - (rsum - rr63)) * inv));
        g3[1] = 1.f / (1.f + expf(-(sumd2 - rsum) * inv));
        g3[2] = 1.f / (1.f + expf(-(sumd2 - (rsum - rr0)) * inv));
    }
    __syncthreads();

    if (tid < WVn) {
        const int u = tid, u0 = u % Vn;
        const float* gr = graph + (s * Vn + u0) * Vn;
        float av[Vn];
        float mx = -1e30f;
#pragma unroll
        for (int v = 0; v < Vn; ++v) {
            float a = attL[u * 33 + v] * (1.f / 512.f);
            av[v] = (gr[v] > 0.f) ? a : -1e30f;
            mx = fmaxf(mx, av[v]);
        }
        float ssum = 0.f;
#pragma unroll
        for (int v = 0; v < Vn; ++v) {
            float e = (av[v] > -1e29f) ? expf(av[v] - mx) : 0.f;
            av[v] = e;
            ssum += e;
        }
        const float sc = g3[u % Wn] / ssum;
        const float* a0 = att0 + (s * WVn + u) * Vn;
#pragma unroll
        for (int v = 0; v < Vn; ++v) attL[u * 33 + v] = av[v] * sc + a0[v];
    }
    __syncthreads();

    unsigned short* ab = attB + ((size_t)(n * Sn + s)) * 32 * 96;
    for (int i = tid; i < 32 * 96; i += 256) {
        const int v = i / 96, kk = i % 96;
        const int w2 = kk >> 5, vp = kk & 31;
        float val = (v < Vn && vp < Vn) ? attL[(w2 * Vn + vp) * 33 + v] : 0.f;
        ab[i] = f2bf(val);
    }
}

// ---------------------------------------------------------------------------
// K_trans: x (N,C,V,T fp32) -> xT[n][t][c][v-swz] bf16 (4KB per (n,t) slab).
// ---------------------------------------------------------------------------
__global__ __launch_bounds__(256) void k_trans(const float* __restrict__ x,
                                               unsigned short* __restrict__ xT) {
    const int n = blockIdx.x, cb = blockIdx.y;  // 16 chunks of 4 c
    const int c0 = cb * 4;
    const int tid = threadIdx.x;
    __shared__ unsigned short XL[4][25][66];    // [cl][v][t] pad 66

    for (int i = tid; i < 1600; i += 256) {
        const int piece = i & 15, row = i >> 4;     // row = cl*25 + v
        const int cl = row / 25, v = row - cl * 25;
        const float4 d = *(const float4*)(x +
            ((size_t)((n * Cn + c0 + cl) * Vn + v)) * Tn + piece * 4);
        unsigned short* dst = &XL[cl][v][piece * 4];
        dst[0] = f2bf(d.x); dst[1] = f2bf(d.y); dst[2] = f2bf(d.z); dst[3] = f2bf(d.w);
    }
    __syncthreads();
    for (int j = tid; j < 1024; j += 256) {     // 64t x 4cl x 4 chunks
        const int p = j & 3, cl = (j >> 2) & 3, t = j >> 4;
        const int v0 = (p ^ cl) * 8;
        unsigned short buf[8];
#pragma unroll
        for (int jj = 0; jj < 8; ++jj) {
            const int v = v0 + jj;
            buf[jj] = (v < Vn) ? XL[cl][v][t] : (unsigned short)0;
        }
        *(s16x8*)(xT + ((size_t)(n * Tn + t) * 2048) + (c0 + cl) * 32 + p * 8) =
            *(const s16x8*)buf;
    }
}

// ---------------------------------------------------------------------------
// K_main8: block = one (n,t), 4 waves, 3 blocks/CU. vs k_main7:
//  - out_w frags (16) hoisted to kernel top (latency hides under staging)
//  - attB frags for BOTH s prefetched right after barrier, before LDS reads
//  - xs3 re-strided to 40 shorts/c-row (odd-20-dword) -> af reads ~2-way
// ---------------------------------------------------------------------------
__global__ __launch_bounds__(256, 3) void k_main8(
    const unsigned short* __restrict__ xT, const unsigned short* __restrict__ attB,
    const unsigned short* __restrict__ out_wbf, const float* __restrict__ out_b,
    const float* __restrict__ og, const float* __restrict__ obeta,
    const float* __restrict__ orm, const float* __restrict__ orv,
    const unsigned short* __restrict__ ff_wbf, const float* __restrict__ ff_b,
    const float* __restrict__ fg, const float* __restrict__ fbeta,
    const float* __restrict__ frm, const float* __restrict__ frv,
    float* __restrict__ out) {
    const int n = blockIdx.x, t = blockIdx.y;
    const int tid = threadIdx.x;
    const int lane = tid & 63, wv = tid >> 6;
    const int r16 = lane & 15, g4 = lane >> 4;

    __shared__ unsigned short xs3[3 * 2560];   // [kb][c][p]*40-stride, 15.4 KB
    __shared__ unsigned short y2L[32 * 512];   // 32 KB
    __shared__ unsigned short y1L[32 * 64];    // 4 KB
    __shared__ float bnp[384];

    // ---- hoisted loop-invariant out_w frags (global, issued first)
    const int orow = wv * 16 + r16;
    s16x8 wa[16];
#pragma unroll
    for (int ks = 0; ks < 16; ++ks)
        wa[ks] = *(const s16x8*)(out_wbf + (size_t)orow * 512 + ks * 32 + g4 * 8);

    if (tid < 64) {
        int o = tid;
        float so = og[o] * rsqrtf(orv[o] + 1e-5f);
        bnp[o] = so; bnp[64 + o] = obeta[o] - orm[o] * so; bnp[128 + o] = out_b[o];
        float sf = fg[o] * rsqrtf(frv[o] + 1e-5f);
        bnp[192 + o] = sf; bnp[256 + o] = fbeta[o] - frm[o] * sf; bnp[320 + o] = ff_b[o];
    }
    // ---- stage xs3 (768 x 16B chunks, coalesced reads, re-strided writes)
    for (int ch = tid; ch < 768; ch += 256) {
        const int kb = ch >> 8, off = ch & 255;
        const int c = off >> 2, p = off & 3;
        const int tg = t - 1 + kb;
        s16x8 d = (s16x8){0, 0, 0, 0, 0, 0, 0, 0};
        if (tg >= 0 && tg < Tn)
            d = *(const s16x8*)(xT + ((size_t)(n * Tn + tg) * 2048) + off * 8);
        *(s16x8*)&xs3[kb * 2560 + c * 40 + p * 8] = d;
    }
    __syncthreads();

    // ---- prefetch attB frags for BOTH owned subsets (global)
    s16x8 bfr[2][3][2];
#pragma unroll
    for (int si = 0; si < 2; ++si) {
        const unsigned short* aB = attB + ((size_t)(n * Sn + wv * 2 + si)) * 32 * 96;
#pragma unroll
        for (int k = 0; k < 3; ++k)
#pragma unroll
            for (int nt = 0; nt < 2; ++nt)
                bfr[si][k][nt] = *(const s16x8*)(aB + (nt * 16 + r16) * 96 + k * 32 + g4 * 8);
    }

    // ---- phase1: aggregation (wave-private s pair); af read per-m from LDS
#pragma unroll
    for (int si = 0; si < 2; ++si) {
        const int s = wv * 2 + si;
#pragma unroll
        for (int m = 0; m < 4; ++m) {
            const int c = m * 16 + r16;
            f32x4 c0 = (f32x4){0.f, 0.f, 0.f, 0.f};
            f32x4 c1 = (f32x4){0.f, 0.f, 0.f, 0.f};
#pragma unroll
            for (int kb = 0; kb < 3; ++kb) {
                const s16x8 af = *(const s16x8*)&xs3[
                    kb * 2560 + c * 40 + ((g4 ^ (c & 3)) << 3)];
                c0 = MFMA16(af, bfr[si][kb][0], c0);
                c1 = MFMA16(af, bfr[si][kb][1], c1);
            }
            const int cw = m * 16 + g4 * 4;
            s16x4 p0, p1;
#pragma unroll
            for (int r = 0; r < 4; ++r) { p0[r] = f2bf(c0[r]); p1[r] = f2bf(c1[r]); }
            const int v0 = r16, v1 = 16 + r16;
            *(s16x4*)&y2L[v0 * 512 + (s * 8 + ((cw >> 3) ^ (v0 & 7))) * 8 + (cw & 7)] = p0;
            *(s16x4*)&y2L[v1 * 512 + (s * 8 + ((cw >> 3) ^ (v1 & 7))) * 8 + (cw & 7)] = p1;
        }
    }
    __syncthreads();

    // ---- phase2: out-proj GEMM K=512 (weights already in registers)
    f32x4 accO[2];
    accO[0] = (f32x4){0.f, 0.f, 0.f, 0.f};
    accO[1] = (f32x4){0.f, 0.f, 0.f, 0.f};
#pragma unroll
    for (int ks = 0; ks < 16; ++ks) {
        const int cidx = ks * 4 + g4;            // k-chunk 0..63
        const int srow = cidx >> 3, lc = cidx & 7;
#pragma unroll
        for (int na = 0; na < 2; ++na) {
            const int v = na * 16 + r16;
            const s16x8 b = *(const s16x8*)&y2L[v * 512 + (srow * 8 + (lc ^ (v & 7))) * 8];
            accO[na] = MFMA16(wa[ks], b, accO[na]);
        }
    }
    // ---- epi1: y1 = leaky(x + BN(accO)) -> y1L[v][o], cache xv
    float xvc[2][4];
    const int ob = wv * 16 + g4 * 4;
#pragma unroll
    for (int na = 0; na < 2; ++na) {
        const int v = na * 16 + r16;
        s16x4 p;
#pragma unroll
        for (int r = 0; r < 4; ++r) {
            const int o = ob + r;
            const float xv = bf2f(xs3[2560 + o * 40 + ((((v >> 3)) ^ (o & 3)) << 3) + (v & 7)]);
            xvc[na][r] = xv;
            float val = (accO[na][r] + bnp[128 + o]) * bnp[o] + bnp[64 + o];
            float y1 = xv + val;
            y1 = (y1 > 0.f) ? y1 : 0.1f * y1;
            p[r] = f2bf(y1);
        }
        *(s16x4*)&y1L[v * 64 + (((ob >> 3) ^ (v & 7)) << 3) + (ob & 7)] = p;
    }
    __syncthreads();

    // ---- ff: K=64 GEMM
    f32x4 accF[2];
    accF[0] = (f32x4){0.f, 0.f, 0.f, 0.f};
    accF[1] = (f32x4){0.f, 0.f, 0.f, 0.f};
#pragma unroll
    for (int ks = 0; ks < 2; ++ks) {
        const s16x8 fa = *(const s16x8*)(ff_wbf + (size_t)orow * 64 + ks * 32 + g4 * 8);
        const int cidx = ks * 4 + g4;            // o-chunk 0..7
#pragma unroll
        for (int na = 0; na < 2; ++na) {
            const int v = na * 16 + r16;
            const s16x8 b = *(const s16x8*)&y1L[v * 64 + ((cidx ^ (v & 7)) << 3)];
            accF[na] = MFMA16(fa, b, accF[na]);
        }
    }
    // ---- epi2 + store
#pragma unroll
    for (int na = 0; na < 2; ++na) {
        const int v = na * 16 + r16;
        if (v < Vn) {
#pragma unroll
            for (int r = 0; r < 4; ++r) {
                const int o = ob + r;
                const float xv = xvc[na][r];
                float val = (accF[na][r] + bnp[320 + o]) * bnp[192 + o] + bnp[256 + o];
                float y2v = xv + val;
                y2v = (y2v > 0.f) ? y2v : 0.1f * y2v;
                float outv = y2v + xv;
                outv = (outv > 0.f) ? outv : 0.f;
                out[((size_t)(n * Cn + o) * Vn + v) * Tn + t] = outv;
            }
        }
    }
}

// ---------------------------------------------------------------------------
extern "C" void kernel_launch(void* const* d_in, const int* in_sizes, int n_in,
                              void* d_out, int out_size, void* d_ws, size_t ws_size,
                              hipStream_t stream) {
    const float* x       = (const float*)d_in[0];
    const float* graph   = (const float*)d_in[1];
    const float* graph_a = (const float*)d_in[2];
    const float* in_w    = (const float*)d_in[3];
    const float* in_b    = (const float*)d_in[4];
    const float* inup_w  = (const float*)d_in[5];
    const float* inup_b  = (const float*)d_in[6];
    const float* diff_w  = (const float*)d_in[7];
    const float* diff_b  = (const float*)d_in[8];
    const float* att0    = (const float*)d_in[9];
    const float* out_w   = (const float*)d_in[10];
    const float* out_b   = (const float*)d_in[11];
    const float* og      = (const float*)d_in[12];
    const float* obeta   = (const float*)d_in[13];
    const float* orm     = (const float*)d_in[14];
    const float* orv     = (const float*)d_in[15];
    const float* ff_w    = (const float*)d_in[16];
    const float* ff_b    = (const float*)d_in[17];
    const float* fg      = (const float*)d_in[18];
    const float* fbeta   = (const float*)d_in[19];
    const float* frm     = (const float*)d_in[20];
    const float* frv     = (const float*)d_in[21];
    float* out = (float*)d_out;

    // ws layout (bytes): red@0 (64K) | attB@71,680 (3M)
    //   out_wbf@3,217,408 | ff_wbf@3,282,944 | pq@3,291,136 | pk@16,398,336
    //   xT ALIASES pq/pk (dead after k_att3): xT@3,291,136
    char* wsb = (char*)d_ws;
    float* red_ws  = (float*)(wsb);
    unsigned short* attB = (unsigned short*)(wsb + 71680);
    unsigned short* owb  = (unsigned short*)(wsb + 3217408);
    unsigned short* fwb  = (unsigned short*)(wsb + 3282944);
    unsigned short* pq = (unsigned short*)(wsb + 3291136);
    unsigned short* pk = (unsigned short*)(wsb + 16398336);
    unsigned short* xT = (unsigned short*)(wsb + 3291136);

    k_red<<<dim3(Cn, Nn), 64, 0, stream>>>(x, graph_a, out_w, ff_w, red_ws, owb, fwb);
    k_proj<<<dim3(Vn, Nn), 256, 0, stream>>>(x, in_w, in_b, inup_w, inup_b, pk, pq);
    k_att3<<<dim3(Nn, Sn), 256, 0, stream>>>(pq, pk, inup_b, graph, att0,
                                             red_ws, diff_w, diff_b, attB);
    k_trans<<<dim3(Nn, 16), 256, 0, stream>>>(x, xT);
    k_main8<<<dim3(Nn, Tn), 256, 0, stream>>>(xT, attB, owb, out_b, og, obeta,
                                              orm, orv, fwb, ff_b, fg, fbeta,
                                              frm, frv, out);
}

// Round 10
// 127.021 us; speedup vs baseline: 1.2268x; 1.2268x over previous
//
#include <hip/hip_runtime.h>
#include <hip/hip_bf16.h>
#include <math.h>

#define Nn 64
#define Cn 64
#define Tn 64
#define Vn 25
#define Sn 8
#define ICn 8
#define Wn 3
#define WVn 75

typedef __attribute__((ext_vector_type(8))) short s16x8;   // 8 bf16 (4 VGPR)
typedef __attribute__((ext_vector_type(4))) short s16x4;   // 4 bf16 (2 VGPR)
typedef __attribute__((ext_vector_type(4))) float f32x4;   // MFMA acc

#define MFMA16(a, b, c) __builtin_amdgcn_mfma_f32_16x16x32_bf16(a, b, c, 0, 0, 0)

static __device__ inline unsigned short f2bf(float f) {
    __hip_bfloat16 h = __float2bfloat16(f);
    return *reinterpret_cast<unsigned short*>(&h);
}
static __device__ inline float bf2f(unsigned short u) {
    union { unsigned int i; float f; } x;
    x.i = ((unsigned int)u) << 16;
    return x.f;
}

// ---------------------------------------------------------------------------
// K1: per (n,c) reductions over x rows (collapsed diff/gate branch).
// n==0 blocks also convert out_w/ff_w rows to bf16 (folded k_conv).
// ---------------------------------------------------------------------------
__global__ __launch_bounds__(64) void k_red(const float* __restrict__ x,
                                            const float* __restrict__ ga,
                                            const float* __restrict__ ow,
                                            const float* __restrict__ fw,
                                            float* __restrict__ red,
                                            unsigned short* __restrict__ owb,
                                            unsigned short* __restrict__ fwb) {
    const int c = blockIdx.x, n = blockIdx.y;
    const int lane = threadIdx.x;
    if (n == 0) {
        for (int j = lane; j < 512; j += 64) owb[c * 512 + j] = f2bf(ow[c * 512 + j]);
        fwb[c * 64 + lane] = f2bf(fw[c * 64 + lane]);
    }
    float rs = 0.f, r0 = 0.f, r63 = 0.f, xg = 0.f;
    if (lane < Vn) {
        const float* row = x + ((size_t)(n * Cn + c) * Vn + lane) * Tn;
        float g = 0.f;
        for (int j = 0; j < Vn; ++j) g += ga[lane * Vn + j];
        for (int t = 0; t < Tn; ++t) rs += row[t];
        r0 = row[0];
        r63 = row[Tn - 1];
        xg = rs * g;
    }
    for (int off = 32; off > 0; off >>= 1) {
        rs += __shfl_down(rs, off);
        r0 += __shfl_down(r0, off);
        r63 += __shfl_down(r63, off);
        xg += __shfl_down(xg, off);
    }
    if (lane == 0) {
        float* p = red + (size_t)(n * Cn + c) * 4;
        p[0] = rs; p[1] = r0; p[2] = r63; p[3] = xg;
    }
}

// ---------------------------------------------------------------------------
// K_proj2 (MFMA): q/k conv1x1 projections -> bf16 [n][v][t][o].
// Per (n,v) block: A = [128 o2][64 c] weights (k rows 0..63, q rows 64..127),
// B = x[n,:,v,:] transposed to [64 t][64 c]; C = [o2][t] -> transposed via
// LDS -> coalesced b128 stores. All LDS tiles chunk-XOR swizzled (2-way max).
// ---------------------------------------------------------------------------
__global__ __launch_bounds__(256) void k_proj2(
    const float* __restrict__ x,
    const float* __restrict__ in_w, const float* __restrict__ in_b,
    const float* __restrict__ inup_w, const float* __restrict__ inup_b,
    unsigned short* __restrict__ pk, unsigned short* __restrict__ pq) {
    const int n = blockIdx.x, v = blockIdx.y;
    const int tid = threadIdx.x;
    const int lane = tid & 63, wv = tid >> 6;
    const int r16 = lane & 15, g4 = lane >> 4;

    __shared__ unsigned short WL[128 * 64];   // [o2][c-chunk ^ (o2&7)] 16 KB
    __shared__ unsigned short XT[64 * 64];    // [t][c-chunk ^ (t&7)]   8 KB
    __shared__ unsigned short CL[64 * 128];   // [t][o2-chunk ^ (t&7)] 16 KB
    __shared__ float bias[128];

    if (tid < 128) bias[tid] = (tid < 64) ? in_b[tid] : inup_b[tid - 64];

    // ---- stage weights: 2048 float4-reads of 16 lanes/row (256B coalesced)
    for (int idx = tid; idx < 2048; idx += 256) {
        const int o2 = idx >> 4, c4 = idx & 15;
        const float4 d = (o2 < 64)
            ? *(const float4*)(in_w + o2 * 64 + c4 * 4)
            : *(const float4*)(inup_w + (o2 - 64) * 64 + c4 * 4);
        s16x4 p;
        p[0] = (short)f2bf(d.x); p[1] = (short)f2bf(d.y);
        p[2] = (short)f2bf(d.z); p[3] = (short)f2bf(d.w);
        const int ch = c4 >> 1;
        *(s16x4*)&WL[o2 * 64 + (((ch ^ (o2 & 7))) << 3) + (c4 & 1) * 4] = p;
    }
    // ---- stage x (c-rows contiguous along t), write transposed [t][c]
    for (int idx = tid; idx < 1024; idx += 256) {
        const int c = idx >> 4, t4 = idx & 15;
        const float4 d = *(const float4*)(x +
            ((size_t)((n * Cn + c) * Vn + v)) * Tn + t4 * 4);
        const float dv[4] = {d.x, d.y, d.z, d.w};
#pragma unroll
        for (int jj = 0; jj < 4; ++jj) {
            const int t = t4 * 4 + jj;
            XT[t * 64 + (((c >> 3) ^ (t & 7)) << 3) + (c & 7)] = f2bf(dv[jj]);
        }
    }
    __syncthreads();

    // ---- MFMA: wave wv owns M-tiles {2wv, 2wv+1} x 4 N-tiles x K=64
#pragma unroll
    for (int mi = 0; mi < 2; ++mi) {
        const int mt = wv * 2 + mi;
        const int o2r = mt * 16 + r16;
#pragma unroll
        for (int nt2 = 0; nt2 < 4; ++nt2) {
            const int t = nt2 * 16 + r16;
            f32x4 acc = (f32x4){0.f, 0.f, 0.f, 0.f};
#pragma unroll
            for (int ks = 0; ks < 2; ++ks) {
                const int ch = ks * 4 + g4;
                const s16x8 a = *(const s16x8*)&WL[o2r * 64 + ((ch ^ (o2r & 7)) << 3)];
                const s16x8 b = *(const s16x8*)&XT[t * 64 + ((ch ^ (t & 7)) << 3)];
                acc = MFMA16(a, b, acc);
            }
            // C: rows o2 = mt*16+g4*4+r, col t (=nt2*16+r16) -> CL[t][o2]
            const int tcol = nt2 * 16 + r16;
            const int ob = mt * 16 + g4 * 4;
            s16x4 p;
#pragma unroll
            for (int r = 0; r < 4; ++r) p[r] = f2bf(acc[r] + bias[ob + r]);
            const int ch = ob >> 3;
            *(s16x4*)&CL[tcol * 128 + ((ch ^ (tcol & 7)) << 3) + (ob & 7)] = p;
        }
    }
    __syncthreads();

    // ---- coalesced stores: 1024 b128 chunks (t, p): p<8 -> pk, p>=8 -> pq
    for (int j = tid; j < 1024; j += 256) {
        const int p = j & 15, t = j >> 4;
        const s16x8 d = *(const s16x8*)&CL[t * 128 + ((p ^ (t & 7)) << 3)];
        const int po = p & 7;
        unsigned short* dst = (p < 8) ? pk : pq;
        *(s16x8*)(dst + (((size_t)(n * Vn + v) * Tn + t) << 6) + po * 8) = d;
    }
}

// ---------------------------------------------------------------------------
// K_att3 (MFMA): fused attention logits + softmax + gate + att0 -> attB.
// Gate computation folded in (from red_ws; hidden under staging/MFMA).
// ---------------------------------------------------------------------------
__global__ __launch_bounds__(256) void k_att3(
    const unsigned short* __restrict__ pq, const unsigned short* __restrict__ pk,
    const float* __restrict__ inup_b, const float* __restrict__ graph,
    const float* __restrict__ att0, const float* __restrict__ red,
    const float* __restrict__ diff_w, const float* __restrict__ diff_b,
    unsigned short* __restrict__ attB) {
    const int n = blockIdx.x, s = blockIdx.y;
    const int tid = threadIdx.x;
    const int lane = tid & 63, wv = tid >> 6;
    const int r16 = lane & 15, g4 = lane >> 4;

    __shared__ unsigned short QS[25 * 536];   // [uu][slot 0..66][cc]
    __shared__ unsigned short KS[32 * 512];   // [v][(t^(v&7))*8+cc]
    __shared__ float attL[80 * 33];
    __shared__ float gp4[8][4];
    __shared__ float g3[3];

    // ---- gate partials (folded k_gate), parallel to staging
    if (tid < 8) {
        const int oc = s * ICn + tid;
        float a = 0.f;
        for (int c = 0; c < Cn; ++c)
            a += red[(n * Cn + c) * 4 + 3] * diff_w[oc * Cn + c];
        gp4[tid][0] = a + 1600.f * diff_b[oc];
        gp4[tid][1] = red[(n * Cn + oc) * 4 + 0];
        gp4[tid][2] = red[(n * Cn + oc) * 4 + 1];
        gp4[tid][3] = red[(n * Cn + oc) * 4 + 2];
    }
    for (int i = tid; i < 2048; i += 256) {
        const int t = i & 63, v = i >> 6;
        s16x8 d = (s16x8){0, 0, 0, 0, 0, 0, 0, 0};
        if (v < Vn)
            d = *(const s16x8*)(pk + (((size_t)(n * Vn + v) * Tn + t) << 6) + s * ICn);
        *(s16x8*)&KS[v * 512 + ((t ^ (v & 7)) << 3)] = d;
    }
    for (int i = tid; i < 1600; i += 256) {
        const int t = i & 63, uu = i >> 6;
        const s16x8 d = *(const s16x8*)(pq +
            (((size_t)(n * Vn + uu) * Tn + t) << 6) + s * ICn);
        *(s16x8*)&QS[uu * 536 + (t + 1) * 8] = d;
    }
    if (tid < 50) {  // bias edge slots 0 and 65
        const int uu = tid >> 1, slot = (tid & 1) * 65;
#pragma unroll
        for (int cc = 0; cc < ICn; ++cc)
            QS[uu * 536 + slot * 8 + cc] = f2bf(inup_b[s * ICn + cc]);
    }
    __syncthreads();

    for (int tile = wv; tile < 10; tile += 4) {
        const int mt = tile >> 1, nt = tile & 1;
        const int u = mt * 16 + r16;
        const int w = u / 25, uu = u % 25;
        const int v = nt * 16 + r16;
        const unsigned short* qbase = &QS[uu * 536 + (g4 + w) * 8];
        const unsigned short* kbase = &KS[v * 512];
        f32x4 acc = (f32x4){0.f, 0.f, 0.f, 0.f};
#pragma unroll
        for (int kb = 0; kb < 16; ++kb) {
            const s16x8 af = *(const s16x8*)(qbase + kb * 32);
            const s16x8 bf = *(const s16x8*)(kbase + (((kb * 4 + g4) ^ (v & 7)) << 3));
            acc = MFMA16(af, bf, acc);
        }
#pragma unroll
        for (int r = 0; r < 4; ++r)
            attL[(mt * 16 + g4 * 4 + r) * 33 + v] = acc[r];
    }
    if (tid == 0) {  // finish gate (parallel to other waves' MFMA)
        float sumd2 = 0.f, rsum = 0.f, rr0 = 0.f, rr63 = 0.f;
#pragma unroll
        for (int cc = 0; cc < 8; ++cc) {
            sumd2 += gp4[cc][0]; rsum += gp4[cc][1];
            rr0 += gp4[cc][2]; rr63 += gp4[cc][3];
        }
        const float inv = 1.f / 12800.f;
        g3[0] = 1.f / (1.f + expf(-(sumd2 - (rsum - rr63)) * inv));
        g3[1] = 1.f / (1.f + expf(-(sumd2 - rsum) * inv));
        g3[2] = 1.f / (1.f + expf(-(sumd2 - (rsum - rr0)) * inv));
    }
    __syncthreads();

    if (tid < WVn) {
        const int u = tid, u0 = u % Vn;
        const float* gr = graph + (s * Vn + u0) * Vn;
        float av[Vn];
        float mx = -1e30f;
#pragma unroll
        for (int v = 0; v < Vn; ++v) {
            float a = attL[u * 33 + v] * (1.f / 512.f);
            av[v] = (gr[v] > 0.f) ? a : -1e30f;
            mx = fmaxf(mx, av[v]);
        }
        float ssum = 0.f;
#pragma unroll
        for (int v = 0; v < Vn; ++v) {
            float e = (av[v] > -1e29f) ? expf(av[v] - mx) : 0.f;
            av[v] = e;
            ssum += e;
        }
        const float sc = g3[u % Wn] / ssum;
        const float* a0 = att0 + (s * WVn + u) * Vn;
#pragma unroll
        for (int v = 0; v < Vn; ++v) attL[u * 33 + v] = av[v] * sc + a0[v];
    }
    __syncthreads();

    unsigned short* ab = attB + ((size_t)(n * Sn + s)) * 32 * 96;
    for (int i = tid; i < 32 * 96; i += 256) {
        const int v = i / 96, kk = i % 96;
        const int w2 = kk >> 5, vp = kk & 31;
        float val = (v < Vn && vp < Vn) ? attL[(w2 * Vn + vp) * 33 + v] : 0.f;
        ab[i] = f2bf(val);
    }
}

// ---------------------------------------------------------------------------
// K_trans: x (N,C,V,T fp32) -> xT[n][t][c][v-swz] bf16 (4KB per (n,t) slab).
// ---------------------------------------------------------------------------
__global__ __launch_bounds__(256) void k_trans(const float* __restrict__ x,
                                               unsigned short* __restrict__ xT) {
    const int n = blockIdx.x, cb = blockIdx.y;  // 16 chunks of 4 c
    const int c0 = cb * 4;
    const int tid = threadIdx.x;
    __shared__ unsigned short XL[4][25][66];    // [cl][v][t] pad 66

    for (int i = tid; i < 1600; i += 256) {
        const int piece = i & 15, row = i >> 4;     // row = cl*25 + v
        const int cl = row / 25, v = row - cl * 25;
        const float4 d = *(const float4*)(x +
            ((size_t)((n * Cn + c0 + cl) * Vn + v)) * Tn + piece * 4);
        unsigned short* dst = &XL[cl][v][piece * 4];
        dst[0] = f2bf(d.x); dst[1] = f2bf(d.y); dst[2] = f2bf(d.z); dst[3] = f2bf(d.w);
    }
    __syncthreads();
    for (int j = tid; j < 1024; j += 256) {     // 64t x 4cl x 4 chunks
        const int p = j & 3, cl = (j >> 2) & 3, t = j >> 4;
        const int v0 = (p ^ cl) * 8;
        unsigned short buf[8];
#pragma unroll
        for (int jj = 0; jj < 8; ++jj) {
            const int v = v0 + jj;
            buf[jj] = (v < Vn) ? XL[cl][v][t] : (unsigned short)0;
        }
        *(s16x8*)(xT + ((size_t)(n * Tn + t) * 2048) + (c0 + cl) * 32 + p * 8) =
            *(const s16x8*)buf;
    }
}

// ---------------------------------------------------------------------------
// K_main7 (reverted to R8's 76us version): block = one (n,t), 4 waves,
// 3 blocks/CU. phase1 aggregation (wave-private s pair) -> y2L; phase2
// K=512 out-proj GEMM; epi1 -> y1L; ff K=64; epi2 -> out.
// ---------------------------------------------------------------------------
__global__ __launch_bounds__(256, 3) void k_main7(
    const unsigned short* __restrict__ xT, const unsigned short* __restrict__ attB,
    const unsigned short* __restrict__ out_wbf, const float* __restrict__ out_b,
    const float* __restrict__ og, const float* __restrict__ obeta,
    const float* __restrict__ orm, const float* __restrict__ orv,
    const unsigned short* __restrict__ ff_wbf, const float* __restrict__ ff_b,
    const float* __restrict__ fg, const float* __restrict__ fbeta,
    const float* __restrict__ frm, const float* __restrict__ frv,
    float* __restrict__ out) {
    const int n = blockIdx.x, t = blockIdx.y;
    const int tid = threadIdx.x;
    const int lane = tid & 63, wv = tid >> 6;
    const int r16 = lane & 15, g4 = lane >> 4;

    __shared__ unsigned short xs3[3 * 2048];   // 12 KB
    __shared__ unsigned short y2L[32 * 512];   // 32 KB
    __shared__ unsigned short y1L[32 * 64];    // 4 KB
    __shared__ float bnp[384];

    if (tid < 64) {
        int o = tid;
        float so = og[o] * rsqrtf(orv[o] + 1e-5f);
        bnp[o] = so; bnp[64 + o] = obeta[o] - orm[o] * so; bnp[128 + o] = out_b[o];
        float sf = fg[o] * rsqrtf(frv[o] + 1e-5f);
        bnp[192 + o] = sf; bnp[256 + o] = fbeta[o] - frm[o] * sf; bnp[320 + o] = ff_b[o];
    }
    // ---- stage xs3 (768 x 16B chunks, coalesced)
    for (int ch = tid; ch < 768; ch += 256) {
        const int kb = ch >> 8, off = ch & 255;
        const int tg = t - 1 + kb;
        s16x8 d = (s16x8){0, 0, 0, 0, 0, 0, 0, 0};
        if (tg >= 0 && tg < Tn)
            d = *(const s16x8*)(xT + ((size_t)(n * Tn + tg) * 2048) + off * 8);
        *(s16x8*)&xs3[ch * 8] = d;
    }
    __syncthreads();

    // ---- phase1: aggregation (wave-private s pair)
    s16x8 af[4][3];
#pragma unroll
    for (int m = 0; m < 4; ++m) {
        const int c = m * 16 + r16;
#pragma unroll
        for (int kb = 0; kb < 3; ++kb)
            af[m][kb] = *(const s16x8*)&xs3[kb * 2048 + c * 32 + ((g4 ^ (c & 3)) << 3)];
    }
#pragma unroll
    for (int si = 0; si < 2; ++si) {
        const int s = wv * 2 + si;
        const unsigned short* aB = attB + ((size_t)(n * Sn + s)) * 32 * 96;
        s16x8 bfr[3][2];
#pragma unroll
        for (int k = 0; k < 3; ++k)
#pragma unroll
            for (int nt = 0; nt < 2; ++nt)
                bfr[k][nt] = *(const s16x8*)(aB + (nt * 16 + r16) * 96 + k * 32 + g4 * 8);
#pragma unroll
        for (int m = 0; m < 4; ++m) {
            f32x4 c0 = (f32x4){0.f, 0.f, 0.f, 0.f};
            f32x4 c1 = (f32x4){0.f, 0.f, 0.f, 0.f};
#pragma unroll
            for (int kb = 0; kb < 3; ++kb) {
                c0 = MFMA16(af[m][kb], bfr[kb][0], c0);
                c1 = MFMA16(af[m][kb], bfr[kb][1], c1);
            }
            const int cw = m * 16 + g4 * 4;
            s16x4 p0, p1;
#pragma unroll
            for (int r = 0; r < 4; ++r) { p0[r] = f2bf(c0[r]); p1[r] = f2bf(c1[r]); }
            const int v0 = r16, v1 = 16 + r16;
            *(s16x4*)&y2L[v0 * 512 + (s * 8 + ((cw >> 3) ^ (v0 & 7))) * 8 + (cw & 7)] = p0;
            *(s16x4*)&y2L[v1 * 512 + (s * 8 + ((cw >> 3) ^ (v1 & 7))) * 8 + (cw & 7)] = p1;
        }
    }
    __syncthreads();

    // ---- phase2: out-proj GEMM K=512
    f32x4 accO[2];
    accO[0] = (f32x4){0.f, 0.f, 0.f, 0.f};
    accO[1] = (f32x4){0.f, 0.f, 0.f, 0.f};
    const int orow = wv * 16 + r16;
#pragma unroll
    for (int ks = 0; ks < 16; ++ks) {
        const s16x8 wa = *(const s16x8*)(out_wbf + (size_t)orow * 512 + ks * 32 + g4 * 8);
        const int cidx = ks * 4 + g4;            // k-chunk 0..63
        const int srow = cidx >> 3, lc = cidx & 7;
#pragma unroll
        for (int na = 0; na < 2; ++na) {
            const int v = na * 16 + r16;
            const s16x8 b = *(const s16x8*)&y2L[v * 512 + (srow * 8 + (lc ^ (v & 7))) * 8];
            accO[na] = MFMA16(wa, b, accO[na]);
        }
    }
    // ---- epi1: y1 = leaky(x + BN(accO)) -> y1L[v][o], cache xv
    float xvc[2][4];
    const int ob = wv * 16 + g4 * 4;
#pragma unroll
    for (int na = 0; na < 2; ++na) {
        const int v = na * 16 + r16;
        s16x4 p;
#pragma unroll
        for (int r = 0; r < 4; ++r) {
            const int o = ob + r;
            const float xv = bf2f(xs3[2048 + o * 32 + ((((v >> 3)) ^ (o & 3)) << 3) + (v & 7)]);
            xvc[na][r] = xv;
            float val = (accO[na][r] + bnp[128 + o]) * bnp[o] + bnp[64 + o];
            float y1 = xv + val;
            y1 = (y1 > 0.f) ? y1 : 0.1f * y1;
            p[r] = f2bf(y1);
        }
        *(s16x4*)&y1L[v * 64 + (((ob >> 3) ^ (v & 7)) << 3) + (ob & 7)] = p;
    }
    __syncthreads();

    // ---- ff: K=64 GEMM
    f32x4 accF[2];
    accF[0] = (f32x4){0.f, 0.f, 0.f, 0.f};
    accF[1] = (f32x4){0.f, 0.f, 0.f, 0.f};
#pragma unroll
    for (int ks = 0; ks < 2; ++ks) {
        const s16x8 fa = *(const s16x8*)(ff_wbf + (size_t)orow * 64 + ks * 32 + g4 * 8);
        const int cidx = ks * 4 + g4;            // o-chunk 0..7
#pragma unroll
        for (int na = 0; na < 2; ++na) {
            const int v = na * 16 + r16;
            const s16x8 b = *(const s16x8*)&y1L[v * 64 + ((cidx ^ (v & 7)) << 3)];
            accF[na] = MFMA16(fa, b, accF[na]);
        }
    }
    // ---- epi2 + store
#pragma unroll
    for (int na = 0; na < 2; ++na) {
        const int v = na * 16 + r16;
        if (v < Vn) {
#pragma unroll
            for (int r = 0; r < 4; ++r) {
                const int o = ob + r;
                const float xv = xvc[na][r];
                float val = (accF[na][r] + bnp[320 + o]) * bnp[192 + o] + bnp[256 + o];
                float y2v = xv + val;
                y2v = (y2v > 0.f) ? y2v : 0.1f * y2v;
                float outv = y2v + xv;
                outv = (outv > 0.f) ? outv : 0.f;
                out[((size_t)(n * Cn + o) * Vn + v) * Tn + t] = outv;
            }
        }
    }
}

// ---------------------------------------------------------------------------
extern "C" void kernel_launch(void* const* d_in, const int* in_sizes, int n_in,
                              void* d_out, int out_size, void* d_ws, size_t ws_size,
                              hipStream_t stream) {
    const float* x       = (const float*)d_in[0];
    const float* graph   = (const float*)d_in[1];
    const float* graph_a = (const float*)d_in[2];
    const float* in_w    = (const float*)d_in[3];
    const float* in_b    = (const float*)d_in[4];
    const float* inup_w  = (const float*)d_in[5];
    const float* inup_b  = (const float*)d_in[6];
    const float* diff_w  = (const float*)d_in[7];
    const float* diff_b  = (const float*)d_in[8];
    const float* att0    = (const float*)d_in[9];
    const float* out_w   = (const float*)d_in[10];
    const float* out_b   = (const float*)d_in[11];
    const float* og      = (const float*)d_in[12];
    const float* obeta   = (const float*)d_in[13];
    const float* orm     = (const float*)d_in[14];
    const float* orv     = (const float*)d_in[15];
    const float* ff_w    = (const float*)d_in[16];
    const float* ff_b    = (const float*)d_in[17];
    const float* fg      = (const float*)d_in[18];
    const float* fbeta   = (const float*)d_in[19];
    const float* frm     = (const float*)d_in[20];
    const float* frv     = (const float*)d_in[21];
    float* out = (float*)d_out;

    // ws layout (bytes): red@0 (64K) | attB@71,680 (3M)
    //   out_wbf@3,217,408 | ff_wbf@3,282,944 | pq@3,291,136 | pk@16,398,336
    //   xT ALIASES pq/pk (dead after k_att3): xT@3,291,136
    char* wsb = (char*)d_ws;
    float* red_ws  = (float*)(wsb);
    unsigned short* attB = (unsigned short*)(wsb + 71680);
    unsigned short* owb  = (unsigned short*)(wsb + 3217408);
    unsigned short* fwb  = (unsigned short*)(wsb + 3282944);
    unsigned short* pq = (unsigned short*)(wsb + 3291136);
    unsigned short* pk = (unsigned short*)(wsb + 16398336);
    unsigned short* xT = (unsigned short*)(wsb + 3291136);

    k_red<<<dim3(Cn, Nn), 64, 0, stream>>>(x, graph_a, out_w, ff_w, red_ws, owb, fwb);
    k_proj2<<<dim3(Nn, Vn), 256, 0, stream>>>(x, in_w, in_b, inup_w, inup_b, pk, pq);
    k_att3<<<dim3(Nn, Sn), 256, 0, stream>>>(pq, pk, inup_b, graph, att0,
                                             red_ws, diff_w, diff_b, attB);
    k_trans<<<dim3(Nn, 16), 256, 0, stream>>>(x, xT);
    k_main7<<<dim3(Nn, Tn), 256, 0, stream>>>(xT, attB, owb, out_b, og, obeta,
                                              orm, orv, fwb, ff_b, fg, fbeta,
                                              frm, frv, out);
}

// Round 12
// 126.889 us; speedup vs baseline: 1.2281x; 1.0010x over previous
//
#include <hip/hip_runtime.h>
#include <hip/hip_bf16.h>
#include <math.h>

#define Nn 64
#define Cn 64
#define Tn 64
#define Vn 25
#define Sn 8
#define ICn 8
#define Wn 3
#define WVn 75

typedef __attribute__((ext_vector_type(8))) short s16x8;   // 8 bf16 (4 VGPR)
typedef __attribute__((ext_vector_type(4))) short s16x4;   // 4 bf16 (2 VGPR)
typedef __attribute__((ext_vector_type(4))) float f32x4;   // MFMA acc

#define MFMA16(a, b, c) __builtin_amdgcn_mfma_f32_16x16x32_bf16(a, b, c, 0, 0, 0)

static __device__ inline unsigned short f2bf(float f) {
    __hip_bfloat16 h = __float2bfloat16(f);
    return *reinterpret_cast<unsigned short*>(&h);
}
static __device__ inline float bf2f(unsigned short u) {
    union { unsigned int i; float f; } x;
    x.i = ((unsigned int)u) << 16;
    return x.f;
}

// ---------------------------------------------------------------------------
// K1: per (n,c) reductions over x rows (collapsed diff/gate branch).
// n==0 blocks also convert out_w/ff_w rows to bf16 (folded k_conv).
// ---------------------------------------------------------------------------
__global__ __launch_bounds__(64) void k_red(const float* __restrict__ x,
                                            const float* __restrict__ ga,
                                            const float* __restrict__ ow,
                                            const float* __restrict__ fw,
                                            float* __restrict__ red,
                                            unsigned short* __restrict__ owb,
                                            unsigned short* __restrict__ fwb) {
    const int c = blockIdx.x, n = blockIdx.y;
    const int lane = threadIdx.x;
    if (n == 0) {
        for (int j = lane; j < 512; j += 64) owb[c * 512 + j] = f2bf(ow[c * 512 + j]);
        fwb[c * 64 + lane] = f2bf(fw[c * 64 + lane]);
    }
    float rs = 0.f, r0 = 0.f, r63 = 0.f, xg = 0.f;
    if (lane < Vn) {
        const float* row = x + ((size_t)(n * Cn + c) * Vn + lane) * Tn;
        float g = 0.f;
        for (int j = 0; j < Vn; ++j) g += ga[lane * Vn + j];
        for (int t = 0; t < Tn; ++t) rs += row[t];
        r0 = row[0];
        r63 = row[Tn - 1];
        xg = rs * g;
    }
    for (int off = 32; off > 0; off >>= 1) {
        rs += __shfl_down(rs, off);
        r0 += __shfl_down(r0, off);
        r63 += __shfl_down(r63, off);
        xg += __shfl_down(xg, off);
    }
    if (lane == 0) {
        float* p = red + (size_t)(n * Cn + c) * 4;
        p[0] = rs; p[1] = r0; p[2] = r63; p[3] = xg;
    }
}

// ---------------------------------------------------------------------------
// K_proj2 (MFMA): q/k conv1x1 projections -> bf16 [n][v][t][o].
// Per (n,v) block: A = [128 o2][64 c] weights (k rows 0..63, q rows 64..127),
// B = x[n,:,v,:] transposed to [64 t][64 c]; C = [o2][t] -> transposed via
// LDS -> coalesced b128 stores. All LDS tiles chunk-XOR swizzled (2-way max).
// ---------------------------------------------------------------------------
__global__ __launch_bounds__(256) void k_proj2(
    const float* __restrict__ x,
    const float* __restrict__ in_w, const float* __restrict__ in_b,
    const float* __restrict__ inup_w, const float* __restrict__ inup_b,
    unsigned short* __restrict__ pk, unsigned short* __restrict__ pq) {
    const int n = blockIdx.x, v = blockIdx.y;
    const int tid = threadIdx.x;
    const int lane = tid & 63, wv = tid >> 6;
    const int r16 = lane & 15, g4 = lane >> 4;

    __shared__ unsigned short WL[128 * 64];   // [o2][c-chunk ^ (o2&7)] 16 KB
    __shared__ unsigned short XT[64 * 64];    // [t][c-chunk ^ (t&7)]   8 KB
    __shared__ unsigned short CL[64 * 128];   // [t][o2-chunk ^ (t&7)] 16 KB
    __shared__ float bias[128];

    if (tid < 128) bias[tid] = (tid < 64) ? in_b[tid] : inup_b[tid - 64];

    // ---- stage weights: 2048 float4-reads of 16 lanes/row (256B coalesced)
    for (int idx = tid; idx < 2048; idx += 256) {
        const int o2 = idx >> 4, c4 = idx & 15;
        const float4 d = (o2 < 64)
            ? *(const float4*)(in_w + o2 * 64 + c4 * 4)
            : *(const float4*)(inup_w + (o2 - 64) * 64 + c4 * 4);
        s16x4 p;
        p[0] = (short)f2bf(d.x); p[1] = (short)f2bf(d.y);
        p[2] = (short)f2bf(d.z); p[3] = (short)f2bf(d.w);
        const int ch = c4 >> 1;
        *(s16x4*)&WL[o2 * 64 + (((ch ^ (o2 & 7))) << 3) + (c4 & 1) * 4] = p;
    }
    // ---- stage x (c-rows contiguous along t), write transposed [t][c]
    for (int idx = tid; idx < 1024; idx += 256) {
        const int c = idx >> 4, t4 = idx & 15;
        const float4 d = *(const float4*)(x +
            ((size_t)((n * Cn + c) * Vn + v)) * Tn + t4 * 4);
        const float dv[4] = {d.x, d.y, d.z, d.w};
#pragma unroll
        for (int jj = 0; jj < 4; ++jj) {
            const int t = t4 * 4 + jj;
            XT[t * 64 + (((c >> 3) ^ (t & 7)) << 3) + (c & 7)] = f2bf(dv[jj]);
        }
    }
    __syncthreads();

    // ---- MFMA: wave wv owns M-tiles {2wv, 2wv+1} x 4 N-tiles x K=64
#pragma unroll
    for (int mi = 0; mi < 2; ++mi) {
        const int mt = wv * 2 + mi;
        const int o2r = mt * 16 + r16;
#pragma unroll
        for (int nt2 = 0; nt2 < 4; ++nt2) {
            const int t = nt2 * 16 + r16;
            f32x4 acc = (f32x4){0.f, 0.f, 0.f, 0.f};
#pragma unroll
            for (int ks = 0; ks < 2; ++ks) {
                const int ch = ks * 4 + g4;
                const s16x8 a = *(const s16x8*)&WL[o2r * 64 + ((ch ^ (o2r & 7)) << 3)];
                const s16x8 b = *(const s16x8*)&XT[t * 64 + ((ch ^ (t & 7)) << 3)];
                acc = MFMA16(a, b, acc);
            }
            // C: rows o2 = mt*16+g4*4+r, col t (=nt2*16+r16) -> CL[t][o2]
            const int tcol = nt2 * 16 + r16;
            const int ob = mt * 16 + g4 * 4;
            s16x4 p;
#pragma unroll
            for (int r = 0; r < 4; ++r) p[r] = f2bf(acc[r] + bias[ob + r]);
            const int ch = ob >> 3;
            *(s16x4*)&CL[tcol * 128 + ((ch ^ (tcol & 7)) << 3) + (ob & 7)] = p;
        }
    }
    __syncthreads();

    // ---- coalesced stores: 1024 b128 chunks (t, p): p<8 -> pk, p>=8 -> pq
    for (int j = tid; j < 1024; j += 256) {
        const int p = j & 15, t = j >> 4;
        const s16x8 d = *(const s16x8*)&CL[t * 128 + ((p ^ (t & 7)) << 3)];
        const int po = p & 7;
        unsigned short* dst = (p < 8) ? pk : pq;
        *(s16x8*)(dst + (((size_t)(n * Vn + v) * Tn + t) << 6) + po * 8) = d;
    }
}

// ---------------------------------------------------------------------------
// K_att3 (MFMA): fused attention logits + softmax + gate + att0 -> attB.
// Gate computation folded in (from red_ws; hidden under staging/MFMA).
// ---------------------------------------------------------------------------
__global__ __launch_bounds__(256) void k_att3(
    const unsigned short* __restrict__ pq, const unsigned short* __restrict__ pk,
    const float* __restrict__ inup_b, const float* __restrict__ graph,
    const float* __restrict__ att0, const float* __restrict__ red,
    const float* __restrict__ diff_w, const float* __restrict__ diff_b,
    unsigned short* __restrict__ attB) {
    const int n = blockIdx.x, s = blockIdx.y;
    const int tid = threadIdx.x;
    const int lane = tid & 63, wv = tid >> 6;
    const int r16 = lane & 15, g4 = lane >> 4;

    __shared__ unsigned short QS[25 * 536];   // [uu][slot 0..66][cc]
    __shared__ unsigned short KS[32 * 512];   // [v][(t^(v&7))*8+cc]
    __shared__ float attL[80 * 33];
    __shared__ float gp4[8][4];
    __shared__ float g3[3];

    // ---- gate partials (folded k_gate), parallel to staging
    if (tid < 8) {
        const int oc = s * ICn + tid;
        float a = 0.f;
        for (int c = 0; c < Cn; ++c)
            a += red[(n * Cn + c) * 4 + 3] * diff_w[oc * Cn + c];
        gp4[tid][0] = a + 1600.f * diff_b[oc];
        gp4[tid][1] = red[(n * Cn + oc) * 4 + 0];
        gp4[tid][2] = red[(n * Cn + oc) * 4 + 1];
        gp4[tid][3] = red[(n * Cn + oc) * 4 + 2];
    }
    for (int i = tid; i < 2048; i += 256) {
        const int t = i & 63, v = i >> 6;
        s16x8 d = (s16x8){0, 0, 0, 0, 0, 0, 0, 0};
        if (v < Vn)
            d = *(const s16x8*)(pk + (((size_t)(n * Vn + v) * Tn + t) << 6) + s * ICn);
        *(s16x8*)&KS[v * 512 + ((t ^ (v & 7)) << 3)] = d;
    }
    for (int i = tid; i < 1600; i += 256) {
        const int t = i & 63, uu = i >> 6;
        const s16x8 d = *(const s16x8*)(pq +
            (((size_t)(n * Vn + uu) * Tn + t) << 6) + s * ICn);
        *(s16x8*)&QS[uu * 536 + (t + 1) * 8] = d;
    }
    if (tid < 50) {  // bias edge slots 0 and 65
        const int uu = tid >> 1, slot = (tid & 1) * 65;
#pragma unroll
        for (int cc = 0; cc < ICn; ++cc)
            QS[uu * 536 + slot * 8 + cc] = f2bf(inup_b[s * ICn + cc]);
    }
    __syncthreads();

    for (int tile = wv; tile < 10; tile += 4) {
        const int mt = tile >> 1, nt = tile & 1;
        const int u = mt * 16 + r16;
        const int w = u / 25, uu = u % 25;
        const int v = nt * 16 + r16;
        const unsigned short* qbase = &QS[uu * 536 + (g4 + w) * 8];
        const unsigned short* kbase = &KS[v * 512];
        f32x4 acc = (f32x4){0.f, 0.f, 0.f, 0.f};
#pragma unroll
        for (int kb = 0; kb < 16; ++kb) {
            const s16x8 af = *(const s16x8*)(qbase + kb * 32);
            const s16x8 bf = *(const s16x8*)(kbase + (((kb * 4 + g4) ^ (v & 7)) << 3));
            acc = MFMA16(af, bf, acc);
        }
#pragma unroll
        for (int r = 0; r < 4; ++r)
            attL[(mt * 16 + g4 * 4 + r) * 33 + v] = acc[r];
    }
    if (tid == 0) {  // finish gate (parallel to other waves' MFMA)
        float sumd2 = 0.f, rsum = 0.f, rr0 = 0.f, rr63 = 0.f;
#pragma unroll
        for (int cc = 0; cc < 8; ++cc) {
            sumd2 += gp4[cc][0]; rsum += gp4[cc][1];
            rr0 += gp4[cc][2]; rr63 += gp4[cc][3];
        }
        const float inv = 1.f / 12800.f;
        g3[0] = 1.f / (1.f + expf(-(sumd2 - (rsum - rr63)) * inv));
        g3[1] = 1.f / (1.f + expf(-(sumd2 - rsum) * inv));
        g3[2] = 1.f / (1.f + expf(-(sumd2 - (rsum - rr0)) * inv));
    }
    __syncthreads();

    if (tid < WVn) {
        const int u = tid, u0 = u % Vn;
        const float* gr = graph + (s * Vn + u0) * Vn;
        float av[Vn];
        float mx = -1e30f;
#pragma unroll
        for (int v = 0; v < Vn; ++v) {
            float a = attL[u * 33 + v] * (1.f / 512.f);
            av[v] = (gr[v] > 0.f) ? a : -1e30f;
            mx = fmaxf(mx, av[v]);
        }
        float ssum = 0.f;
#pragma unroll
        for (int v = 0; v < Vn; ++v) {
            float e = (av[v] > -1e29f) ? expf(av[v] - mx) : 0.f;
            av[v] = e;
            ssum += e;
        }
        const float sc = g3[u % Wn] / ssum;
        const float* a0 = att0 + (s * WVn + u) * Vn;
#pragma unroll
        for (int v = 0; v < Vn; ++v) attL[u * 33 + v] = av[v] * sc + a0[v];
    }
    __syncthreads();

    unsigned short* ab = attB + ((size_t)(n * Sn + s)) * 32 * 96;
    for (int i = tid; i < 32 * 96; i += 256) {
        const int v = i / 96, kk = i % 96;
        const int w2 = kk >> 5, vp = kk & 31;
        float val = (v < Vn && vp < Vn) ? attL[(w2 * Vn + vp) * 33 + v] : 0.f;
        ab[i] = f2bf(val);
    }
}

// ---------------------------------------------------------------------------
// K_trans: x (N,C,V,T fp32) -> xT[n][t][c][v-swz] bf16 (4KB per (n,t) slab).
// ---------------------------------------------------------------------------
__global__ __launch_bounds__(256) void k_trans(const float* __restrict__ x,
                                               unsigned short* __restrict__ xT) {
    const int n = blockIdx.x, cb = blockIdx.y;  // 16 chunks of 4 c
    const int c0 = cb * 4;
    const int tid = threadIdx.x;
    __shared__ unsigned short XL[4][25][66];    // [cl][v][t] pad 66

    for (int i = tid; i < 1600; i += 256) {
        const int piece = i & 15, row = i >> 4;     // row = cl*25 + v
        const int cl = row / 25, v = row - cl * 25;
        const float4 d = *(const float4*)(x +
            ((size_t)((n * Cn + c0 + cl) * Vn + v)) * Tn + piece * 4);
        unsigned short* dst = &XL[cl][v][piece * 4];
        dst[0] = f2bf(d.x); dst[1] = f2bf(d.y); dst[2] = f2bf(d.z); dst[3] = f2bf(d.w);
    }
    __syncthreads();
    for (int j = tid; j < 1024; j += 256) {     // 64t x 4cl x 4 chunks
        const int p = j & 3, cl = (j >> 2) & 3, t = j >> 4;
        const int v0 = (p ^ cl) * 8;
        unsigned short buf[8];
#pragma unroll
        for (int jj = 0; jj < 8; ++jj) {
            const int v = v0 + jj;
            buf[jj] = (v < Vn) ? XL[cl][v][t] : (unsigned short)0;
        }
        *(s16x8*)(xT + ((size_t)(n * Tn + t) * 2048) + (c0 + cl) * 32 + p * 8) =
            *(const s16x8*)buf;
    }
}

// ---------------------------------------------------------------------------
// K_main7: block = one (n,t), 4 waves, 3 blocks/CU. phase1 aggregation
// (wave-private s pair) -> y2L; phase2 K=512 out-proj GEMM; epi1 -> y1L;
// ff K=64; epi2 -> out.
// ---------------------------------------------------------------------------
__global__ __launch_bounds__(256, 3) void k_main7(
    const unsigned short* __restrict__ xT, const unsigned short* __restrict__ attB,
    const unsigned short* __restrict__ out_wbf, const float* __restrict__ out_b,
    const float* __restrict__ og, const float* __restrict__ obeta,
    const float* __restrict__ orm, const float* __restrict__ orv,
    const unsigned short* __restrict__ ff_wbf, const float* __restrict__ ff_b,
    const float* __restrict__ fg, const float* __restrict__ fbeta,
    const float* __restrict__ frm, const float* __restrict__ frv,
    float* __restrict__ out) {
    const int n = blockIdx.x, t = blockIdx.y;
    const int tid = threadIdx.x;
    const int lane = tid & 63, wv = tid >> 6;
    const int r16 = lane & 15, g4 = lane >> 4;

    __shared__ unsigned short xs3[3 * 2048];   // 12 KB
    __shared__ unsigned short y2L[32 * 512];   // 32 KB
    __shared__ unsigned short y1L[32 * 64];    // 4 KB
    __shared__ float bnp[384];

    if (tid < 64) {
        int o = tid;
        float so = og[o] * rsqrtf(orv[o] + 1e-5f);
        bnp[o] = so; bnp[64 + o] = obeta[o] - orm[o] * so; bnp[128 + o] = out_b[o];
        float sf = fg[o] * rsqrtf(frv[o] + 1e-5f);
        bnp[192 + o] = sf; bnp[256 + o] = fbeta[o] - frm[o] * sf; bnp[320 + o] = ff_b[o];
    }
    // ---- stage xs3 (768 x 16B chunks, coalesced)
    for (int ch = tid; ch < 768; ch += 256) {
        const int kb = ch >> 8, off = ch & 255;
        const int tg = t - 1 + kb;
        s16x8 d = (s16x8){0, 0, 0, 0, 0, 0, 0, 0};
        if (tg >= 0 && tg < Tn)
            d = *(const s16x8*)(xT + ((size_t)(n * Tn + tg) * 2048) + off * 8);
        *(s16x8*)&xs3[ch * 8] = d;
    }
    __syncthreads();

    // ---- phase1: aggregation (wave-private s pair)
    s16x8 af[4][3];
#pragma unroll
    for (int m = 0; m < 4; ++m) {
        const int c = m * 16 + r16;
#pragma unroll
        for (int kb = 0; kb < 3; ++kb)
            af[m][kb] = *(const s16x8*)&xs3[kb * 2048 + c * 32 + ((g4 ^ (c & 3)) << 3)];
    }
#pragma unroll
    for (int si = 0; si < 2; ++si) {
        const int s = wv * 2 + si;
        const unsigned short* aB = attB + ((size_t)(n * Sn + s)) * 32 * 96;
        s16x8 bfr[3][2];
#pragma unroll
        for (int k = 0; k < 3; ++k)
#pragma unroll
            for (int nt = 0; nt < 2; ++nt)
                bfr[k][nt] = *(const s16x8*)(aB + (nt * 16 + r16) * 96 + k * 32 + g4 * 8);
#pragma unroll
        for (int m = 0; m < 4; ++m) {
            f32x4 c0 = (f32x4){0.f, 0.f, 0.f, 0.f};
            f32x4 c1 = (f32x4){0.f, 0.f, 0.f, 0.f};
#pragma unroll
            for (int kb = 0; kb < 3; ++kb) {
                c0 = MFMA16(af[m][kb], bfr[kb][0], c0);
                c1 = MFMA16(af[m][kb], bfr[kb][1], c1);
            }
            const int cw = m * 16 + g4 * 4;
            s16x4 p0, p1;
#pragma unroll
            for (int r = 0; r < 4; ++r) { p0[r] = f2bf(c0[r]); p1[r] = f2bf(c1[r]); }
            const int v0 = r16, v1 = 16 + r16;
            *(s16x4*)&y2L[v0 * 512 + (s * 8 + ((cw >> 3) ^ (v0 & 7))) * 8 + (cw & 7)] = p0;
            *(s16x4*)&y2L[v1 * 512 + (s * 8 + ((cw >> 3) ^ (v1 & 7))) * 8 + (cw & 7)] = p1;
        }
    }
    __syncthreads();

    // ---- phase2: out-proj GEMM K=512
    f32x4 accO[2];
    accO[0] = (f32x4){0.f, 0.f, 0.f, 0.f};
    accO[1] = (f32x4){0.f, 0.f, 0.f, 0.f};
    const int orow = wv * 16 + r16;
#pragma unroll
    for (int ks = 0; ks < 16; ++ks) {
        const s16x8 wa = *(const s16x8*)(out_wbf + (size_t)orow * 512 + ks * 32 + g4 * 8);
        const int cidx = ks * 4 + g4;            // k-chunk 0..63
        const int srow = cidx >> 3, lc = cidx & 7;
#pragma unroll
        for (int na = 0; na < 2; ++na) {
            const int v = na * 16 + r16;
            const s16x8 b = *(const s16x8*)&y2L[v * 512 + (srow * 8 + (lc ^ (v & 7))) * 8];
            accO[na] = MFMA16(wa, b, accO[na]);
        }
    }
    // ---- epi1: y1 = leaky(x + BN(accO)) -> y1L[v][o], cache xv
    float xvc[2][4];
    const int ob = wv * 16 + g4 * 4;
#pragma unroll
    for (int na = 0; na < 2; ++na) {
        const int v = na * 16 + r16;
        s16x4 p;
#pragma unroll
        for (int r = 0; r < 4; ++r) {
            const int o = ob + r;
            const float xv = bf2f(xs3[2048 + o * 32 + ((((v >> 3)) ^ (o & 3)) << 3) + (v & 7)]);
            xvc[na][r] = xv;
            float val = (accO[na][r] + bnp[128 + o]) * bnp[o] + bnp[64 + o];
            float y1 = xv + val;
            y1 = (y1 > 0.f) ? y1 : 0.1f * y1;
            p[r] = f2bf(y1);
        }
        *(s16x4*)&y1L[v * 64 + (((ob >> 3) ^ (v & 7)) << 3) + (ob & 7)] = p;
    }
    __syncthreads();

    // ---- ff: K=64 GEMM
    f32x4 accF[2];
    accF[0] = (f32x4){0.f, 0.f, 0.f, 0.f};
    accF[1] = (f32x4){0.f, 0.f, 0.f, 0.f};
#pragma unroll
    for (int ks = 0; ks < 2; ++ks) {
        const s16x8 fa = *(const s16x8*)(ff_wbf + (size_t)orow * 64 + ks * 32 + g4 * 8);
        const int cidx = ks * 4 + g4;            // o-chunk 0..7
#pragma unroll
        for (int na = 0; na < 2; ++na) {
            const int v = na * 16 + r16;
            const s16x8 b = *(const s16x8*)&y1L[v * 64 + ((cidx ^ (v & 7)) << 3)];
            accF[na] = MFMA16(fa, b, accF[na]);
        }
    }
    // ---- epi2 + store
#pragma unroll
    for (int na = 0; na < 2; ++na) {
        const int v = na * 16 + r16;
        if (v < Vn) {
#pragma unroll
            for (int r = 0; r < 4; ++r) {
                const int o = ob + r;
                const float xv = xvc[na][r];
                float val = (accF[na][r] + bnp[320 + o]) * bnp[192 + o] + bnp[256 + o];
                float y2v = xv + val;
                y2v = (y2v > 0.f) ? y2v : 0.1f * y2v;
                float outv = y2v + xv;
                outv = (outv > 0.f) ? outv : 0.f;
                out[((size_t)(n * Cn + o) * Vn + v) * Tn + t] = outv;
            }
        }
    }
}

// ---------------------------------------------------------------------------
extern "C" void kernel_launch(void* const* d_in, const int* in_sizes, int n_in,
                              void* d_out, int out_size, void* d_ws, size_t ws_size,
                              hipStream_t stream) {
    const float* x       = (const float*)d_in[0];
    const float* graph   = (const float*)d_in[1];
    const float* graph_a = (const float*)d_in[2];
    const float* in_w    = (const float*)d_in[3];
    const float* in_b    = (const float*)d_in[4];
    const float* inup_w  = (const float*)d_in[5];
    const float* inup_b  = (const float*)d_in[6];
    const float* diff_w  = (const float*)d_in[7];
    const float* diff_b  = (const float*)d_in[8];
    const float* att0    = (const float*)d_in[9];
    const float* out_w   = (const float*)d_in[10];
    const float* out_b   = (const float*)d_in[11];
    const float* og      = (const float*)d_in[12];
    const float* obeta   = (const float*)d_in[13];
    const float* orm     = (const float*)d_in[14];
    const float* orv     = (const float*)d_in[15];
    const float* ff_w    = (const float*)d_in[16];
    const float* ff_b    = (const float*)d_in[17];
    const float* fg      = (const float*)d_in[18];
    const float* fbeta   = (const float*)d_in[19];
    const float* frm     = (const float*)d_in[20];
    const float* frv     = (const float*)d_in[21];
    float* out = (float*)d_out;

    // ws layout (bytes): red@0 (64K) | attB@71,680 (3M) | out_wbf@3,217,408
    //   | ff_wbf@3,282,944 | pq@3,291,136 (13.1M) | pk@16,398,336 (13.1M)
    //   xT ALIASES pq/pk (dead after k_att3; k_trans launched after it).
    char* wsb = (char*)d_ws;
    float* red_ws  = (float*)(wsb);
    unsigned short* attB = (unsigned short*)(wsb + 71680);
    unsigned short* owb  = (unsigned short*)(wsb + 3217408);
    unsigned short* fwb  = (unsigned short*)(wsb + 3282944);
    unsigned short* pq = (unsigned short*)(wsb + 3291136);
    unsigned short* pk = (unsigned short*)(wsb + 16398336);
    unsigned short* xT = (unsigned short*)(wsb + 3291136);

    k_red<<<dim3(Cn, Nn), 64, 0, stream>>>(x, graph_a, out_w, ff_w, red_ws, owb, fwb);
    k_proj2<<<dim3(Nn, Vn), 256, 0, stream>>>(x, in_w, in_b, inup_w, inup_b, pk, pq);
    k_att3<<<dim3(Nn, Sn), 256, 0, stream>>>(pq, pk, inup_b, graph, att0,
                                             red_ws, diff_w, diff_b, attB);
    k_trans<<<dim3(Nn, 16), 256, 0, stream>>>(x, xT);
    k_main7<<<dim3(Nn, Tn), 256, 0, stream>>>(xT, attB, owb, out_b, og, obeta,
                                              orm, orv, fwb, ff_b, fg, fbeta,
                                              frm, frv, out);
}